// Round 12
// baseline (86.323 us; speedup 1.0000x reference)
//
#include <hip/hip_runtime.h>
#include <hip/hip_bf16.h>
#include <cstdint>

#define N 4096
#define CC 256
#define CH 32
#define L2E 1.4426950408889634f

typedef __attribute__((ext_vector_type(8)))  short short8;
typedef __attribute__((ext_vector_type(16))) float f32x16;
typedef __attribute__((ext_vector_type(4)))  uint32_t u32x4;

// ---- workspace float offsets ----
#define OFF_WFRAG 0            // wfragb [6][16 kb][64 lane][8 j] bf16 (as u16)
#define OFF_WEFF  311296       // weff  [2][64][256] fp32
#define OFF_BEFF  344064       // beff  [2][256] fp32
#define OFF_QF    344576       // Qf [2][2][128 nt][2 half][64 lane][8] bf16 (scaled by log2e)
#define OFF_KF    606720       // Kf [2][2][128 nt][2 half][64 lane][8] bf16
#define OFF_VF    868864       // Vf [2][2][128 nt][2 fr  ][64 lane][8] bf16
#define OFF_ANG   1131008      // ANg [4 rb][64 ch][4096 m] bf16 (normalized attn out)

__device__ __forceinline__ uint32_t cvtpk_bf16(float lo, float hi) {
  uint32_t r;
  asm("v_cvt_pk_bf16_f32 %0, %1, %2" : "=v"(r) : "v"(lo), "v"(hi));
  return r;
}
__device__ __forceinline__ float bf2f(uint16_t u) {
  return __builtin_bit_cast(float, (uint32_t)u << 16);
}

// D-layout rows (16 regs, row=(r&3)+8*(r>>2)+4*l5, col=l31) -> two bf16 frags
__device__ __forceinline__ void rows_to_frags(const float* p, u32x4& lo, u32x4& hi) {
#pragma unroll
  for (int kh = 0; kh < 2; ++kh) {
    int base = kh * 8;
    uint32_t x0 = cvtpk_bf16(p[base + 0], p[base + 1]);
    uint32_t y0 = cvtpk_bf16(p[base + 4], p[base + 5]);
    asm volatile("v_permlane32_swap_b32 %0, %1" : "+v"(x0), "+v"(y0));
    uint32_t x1 = cvtpk_bf16(p[base + 2], p[base + 3]);
    uint32_t y1 = cvtpk_bf16(p[base + 6], p[base + 7]);
    asm volatile("v_permlane32_swap_b32 %0, %1" : "+v"(x1), "+v"(y1));
    u32x4 r; r[0] = x0; r[1] = x1; r[2] = y0; r[3] = y1;
    if (kh == 0) lo = r; else hi = r;
  }
}

// one 32-key attention step (verbatim math, validated)
__device__ __forceinline__ void attn_step(short8 ak0, short8 ak1, short8 bv0, short8 bv1,
                                          short8 bq0, short8 bq1,
                                          f32x16& ao, float& lacc, const f32x16& zero16) {
  f32x16 sa = __builtin_amdgcn_mfma_f32_32x32x16_bf16(ak0, bq0, zero16, 0, 0, 0);
  sa = __builtin_amdgcn_mfma_f32_32x32x16_bf16(ak1, bq1, sa, 0, 0, 0);
  float p[16];
#pragma unroll
  for (int r = 0; r < 16; ++r) p[r] = __builtin_amdgcn_exp2f(sa[r]);
  float t0 = 0.f, t1 = 0.f;
#pragma unroll
  for (int r = 0; r < 8; ++r) { t0 += p[2 * r]; t1 += p[2 * r + 1]; }
  lacc += t0 + t1;
  u32x4 lo, hi;
  rows_to_frags(p, lo, hi);
  ao = __builtin_amdgcn_mfma_f32_32x32x16_bf16(__builtin_bit_cast(short8, lo), bv0, ao, 0, 0, 0);
  ao = __builtin_amdgcn_mfma_f32_32x32x16_bf16(__builtin_bit_cast(short8, hi), bv1, ao, 0, 0, 0);
}

// ------------------------------------------------------------------
// 1) prep2: weight MFMA-frag table + Weff/beff directly from wo.
// ------------------------------------------------------------------
__global__ void k_prep2(const float* __restrict__ wf1, const float* __restrict__ wg1,
                        const float* __restrict__ wh1, const float* __restrict__ wf2,
                        const float* __restrict__ wg2, const float* __restrict__ wh2,
                        const float* __restrict__ wo1, const float* __restrict__ wo2,
                        const float* __restrict__ wv11, const float* __restrict__ wv12,
                        const float* __restrict__ wv21, const float* __restrict__ wv22,
                        const float* __restrict__ bv11, const float* __restrict__ bv12,
                        const float* __restrict__ bv21, const float* __restrict__ bv22,
                        const float* __restrict__ bo1, const float* __restrict__ bo2,
                        uint16_t* __restrict__ wfragb, float* __restrict__ weff,
                        float* __restrict__ beff) {
  int bid = blockIdx.x;
  if (bid < 192) {
    int idx = bid * 256 + threadIdx.x;                 // < 49152 u16
    int q = idx >> 13, kb = (idx >> 9) & 15, l = (idx >> 3) & 63, j = idx & 7;
    int ch = l & 31, c = kb * 16 + (l >> 5) * 8 + j;
    const float* w = q == 0 ? wf1 : q == 1 ? wg1 : q == 2 ? wh1
                   : q == 3 ? wf2 : q == 4 ? wg2 : wh2;
    wfragb[idx] = (uint16_t)cvtpk_bf16(w[ch * CC + c], 0.f);
  } else if (bid < 320) {
    int bid2 = bid - 192;
    int r = bid2 >> 6, ch = bid2 & 63, half = ch >> 5, chp = ch & 31;
    int o = threadIdx.x;
    const float* wv = (r == 0) ? (half ? wv12 : wv11) : (half ? wv22 : wv21);
    const float* wrow = (r == 0 ? wo1 : wo2) + (size_t)o * 512 + half * 256;
    float a[8];
#pragma unroll
    for (int u = 0; u < 8; ++u) a[u] = 0.f;
#pragma unroll 4
    for (int c = 0; c < 256; c += 8) {
#pragma unroll
      for (int u = 0; u < 8; ++u)
        a[u] = fmaf(wrow[c + u], wv[(c + u) * CH + chp], a[u]);
    }
    weff[((size_t)r * 64 + ch) * 256 + o] =
        ((a[0] + a[1]) + (a[2] + a[3])) + ((a[4] + a[5]) + (a[6] + a[7]));
  } else {
    int r = bid - 320;
    int o = threadIdx.x;
    const float* bo  = r == 0 ? bo1 : bo2;
    const float* bva = r == 0 ? bv11 : bv21;
    const float* bvb = r == 0 ? bv12 : bv22;
    const float* wrow = (r == 0 ? wo1 : wo2) + (size_t)o * 512;
    float a[4], b4[4];
#pragma unroll
    for (int u = 0; u < 4; ++u) { a[u] = 0.f; b4[u] = 0.f; }
#pragma unroll 8
    for (int c = 0; c < 256; c += 4) {
#pragma unroll
      for (int u = 0; u < 4; ++u) {
        a[u]  = fmaf(wrow[c + u],       bva[c + u], a[u]);
        b4[u] = fmaf(wrow[c + u + 256], bvb[c + u], b4[u]);
      }
    }
    beff[r * 256 + o] = bo[o] + ((a[0] + a[1]) + (a[2] + a[3]))
                              + ((b4[0] + b4[1]) + (b4[2] + b4[3]));
  }
}

// ------------------------------------------------------------------
// 2) projections via MFMA, K-split across wave pairs (validated r10)
// ------------------------------------------------------------------
__global__ __launch_bounds__(256) void k_proj(
    const float* __restrict__ x, const float* __restrict__ y,
    const uint16_t* __restrict__ wfragb,
    const float* __restrict__ bf1, const float* __restrict__ bg1, const float* __restrict__ bh1,
    const float* __restrict__ bf2, const float* __restrict__ bg2, const float* __restrict__ bh2,
    uint16_t* __restrict__ Qf, uint16_t* __restrict__ Kf, uint16_t* __restrict__ Vf) {
  __shared__ float xch[2][64][17];
  int bid = blockIdx.x;
  int w = __builtin_amdgcn_readfirstlane(threadIdx.x >> 6);
  int l = threadIdx.x & 63, l31 = l & 31, l5 = l >> 5;

  int q, ql, b, nt, inst, khalf, pair;
  const float* src;
  const float* bias;
  bool isf, isV;
  if (bid < 512) {
    int chunk = bid >> 1;
    ql = (bid & 1) * 2 + (w >> 1); khalf = w & 1; pair = w >> 1;
    b = chunk >> 7; nt = chunk & 127;
    src = x; inst = 0;
    q = (ql == 3) ? 5 : ql;
    isf = (ql == 0); isV = (ql >= 2);
    bias = ql == 0 ? bf1 : ql == 1 ? bg1 : ql == 2 ? bh1 : bh2;
  } else {
    int u = (bid - 512) * 4 + w;
    int task = u >> 1; khalf = u & 1; pair = w >> 1;
    int chunk = task >> 1; ql = task & 1;
    b = chunk >> 7; nt = chunk & 127;
    src = y; inst = 1;
    q = 3 + ql;
    isf = (ql == 0); isV = false;
    bias = ql == 0 ? bf2 : bg2;
  }

  const u32x4* wp = (const u32x4*)wfragb + (size_t)q * 16 * 64 + (size_t)khalf * 8 * 64 + l;
  u32x4 wfr[8];
#pragma unroll
  for (int kb = 0; kb < 8; ++kb) wfr[kb] = wp[kb * 64];

  const float* sp = src + (size_t)b * CC * N + (size_t)(khalf * 128 + l5 * 8) * N + nt * 32 + l31;
  f32x16 acc;
#pragma unroll
  for (int r = 0; r < 16; ++r) acc[r] = 0.f;

  if (isV) {
#pragma unroll
    for (int kb = 0; kb < 8; ++kb) {
      const float* kp = sp + (size_t)kb * 16 * N;
      float xj[8];
#pragma unroll
      for (int j = 0; j < 8; ++j) xj[j] = kp[(size_t)j * N];
      u32x4 bu;
#pragma unroll
      for (int jh = 0; jh < 4; ++jh) bu[jh] = cvtpk_bf16(xj[2 * jh], xj[2 * jh + 1]);
      acc = __builtin_amdgcn_mfma_f32_32x32x16_bf16(
          __builtin_bit_cast(short8, bu), __builtin_bit_cast(short8, wfr[kb]), acc, 0, 0, 0);
    }
  } else {
#pragma unroll
    for (int kb = 0; kb < 8; ++kb) {
      const float* kp = sp + (size_t)kb * 16 * N;
      float xj[8];
#pragma unroll
      for (int j = 0; j < 8; ++j) xj[j] = kp[(size_t)j * N];
      u32x4 bu;
#pragma unroll
      for (int jh = 0; jh < 4; ++jh) bu[jh] = cvtpk_bf16(xj[2 * jh], xj[2 * jh + 1]);
      acc = __builtin_amdgcn_mfma_f32_32x32x16_bf16(
          __builtin_bit_cast(short8, wfr[kb]), __builtin_bit_cast(short8, bu), acc, 0, 0, 0);
    }
  }

  if (khalf == 1) {
#pragma unroll
    for (int r = 0; r < 16; ++r) xch[pair][l][r] = acc[r];
  }
  __syncthreads();
  if (khalf == 1) return;
#pragma unroll
  for (int r = 0; r < 16; ++r) acc[r] += xch[pair][l][r];

  float p[16];
  if (isV) {
    float bv = bias[l31];
#pragma unroll
    for (int r = 0; r < 16; ++r) p[r] = acc[r] + bv;
  } else {
#pragma unroll
    for (int r = 0; r < 16; ++r) {
      int crow = (r & 3) + 8 * (r >> 2) + 4 * l5;
      float t = acc[r] + bias[crow];
      p[r] = isf ? t * L2E : t;
    }
  }

  u32x4 lo, hi;
  rows_to_frags(p, lo, hi);

  uint16_t* dstb = isV ? Vf : (isf ? Qf : Kf);
  int oinst = isV ? (ql - 2) : inst;               // h1->inst0, h2->inst1
  int b128 = (oinst * 2 + b) * 128 + nt;
  uint32_t* d0 = (uint32_t*)dstb + (size_t)b128 * 512 + l * 4;
  *(u32x4*)d0 = lo;
  *(u32x4*)(d0 + 256) = hi;
}

// ------------------------------------------------------------------
// 3) attention, r12: block = (r, b, ik, qg-pair) => 512 blocks x 8 waves
//    = 2 blocks/CU, 4 waves/SIMD. Wave w = key-eighth (16 tiles),
//    processes BOTH q-tiles of the pair per K/V load (ILP-2, r10's
//    proven reuse). Combine over 8 kw, normalize, write bf16 ANg.
// ------------------------------------------------------------------
__global__ __launch_bounds__(512) void k_attn8(const uint16_t* __restrict__ Qf,
                                               const uint16_t* __restrict__ Kf,
                                               const uint16_t* __restrict__ Vf,
                                               uint16_t* __restrict__ ANg) {
  __shared__ uint16_t redAO[8][2][32][34];     // [kw][qi][query][channel] bf16
  __shared__ float    redL[8][2][32];
  int bid = blockIdx.x;
  int qg = bid & 63, t2 = bid >> 6, ik = t2 & 1, rb = t2 >> 1;
  int r = rb >> 1, b = rb & 1;
  int tid = threadIdx.x;
  int w = __builtin_amdgcn_readfirstlane(tid >> 6);  // kw eighth
  int l = tid & 63, l31 = l & 31, l5 = l >> 5;
  int qt0 = qg * 2, qt1 = qg * 2 + 1;

  const uint16_t* Qp0 = Qf + (size_t)((r * 2 + b) * 128 + qt0) * 1024 + l * 8;
  const uint16_t* Qp1 = Qf + (size_t)((r * 2 + b) * 128 + qt1) * 1024 + l * 8;
  const uint16_t* Kp = Kf + (size_t)((ik * 2 + b) * 128 + w * 16) * 1024 + l * 8;
  const uint16_t* Vp = Vf + (size_t)((ik * 2 + b) * 128 + w * 16) * 1024 + l * 8;

  short8 bq00 = *(const short8*)(Qp0);
  short8 bq01 = *(const short8*)(Qp0 + 512);
  short8 bq10 = *(const short8*)(Qp1);
  short8 bq11 = *(const short8*)(Qp1 + 512);

  f32x16 zero16, ao0, ao1;
#pragma unroll
  for (int rr = 0; rr < 16; ++rr) { zero16[rr] = 0.f; ao0[rr] = 0.f; ao1[rr] = 0.f; }
  float lacc0 = 0.f, lacc1 = 0.f;

  for (int t = 0; t < 16; ++t) {
    const uint16_t* kt = Kp + t * 1024;
    short8 ak0 = *(const short8*)(kt);
    short8 ak1 = *(const short8*)(kt + 512);
    const uint16_t* vt = Vp + t * 1024;
    short8 bv0 = *(const short8*)(vt);
    short8 bv1 = *(const short8*)(vt + 512);
    attn_step(ak0, ak1, bv0, bv1, bq00, bq01, ao0, lacc0, zero16);
    attn_step(ak0, ak1, bv0, bv1, bq10, bq11, ao1, lacc1, zero16);
  }

  // per-wave partials -> LDS (bf16)  (row = query, col = channel)
#pragma unroll
  for (int rr = 0; rr < 16; ++rr) {
    int row = (rr & 3) + 8 * (rr >> 2) + 4 * l5;
    redAO[w][0][row][l31] = (uint16_t)cvtpk_bf16(ao0[rr], ao0[rr]);
    redAO[w][1][row][l31] = (uint16_t)cvtpk_bf16(ao1[rr], ao1[rr]);
  }
  lacc0 += __shfl_xor(lacc0, 32);
  lacc1 += __shfl_xor(lacc1, 32);
  if (l < 32) {
    redL[w][0][l31] = lacc0;
    redL[w][1][l31] = lacc1;
  }
  __syncthreads();

  // combine over kw + normalize + write ANg[rb][ik*32+chp][qg*64 + m]
  {
    int chp = tid >> 4, mi = tid & 15;               // chp 0..31, 4 m each
    uint16_t* dst = ANg + ((size_t)rb * 64 + ik * 32 + chp) * N + qg * 64;
#pragma unroll
    for (int mm = 0; mm < 4; ++mm) {
      int m = mi * 4 + mm;
      int qi = m >> 5, mq = m & 31;
      float L = 0.f, s = 0.f;
#pragma unroll
      for (int kw = 0; kw < 8; ++kw) {
        L += redL[kw][qi][mq];
        s += bf2f(redAO[kw][qi][mq][chp]);
      }
      float v = s * __builtin_amdgcn_rcpf(L);
      dst[m] = (uint16_t)cvtpk_bf16(v, v);
    }
  }
}

// ------------------------------------------------------------------
// 4) epilogue (r11's validated math, AN staged from global):
//    block = (r, b, qt) -> 512 blocks x 512 thr. out 256 o x 32 m.
// ------------------------------------------------------------------
__global__ __launch_bounds__(512) void k_epi2(const uint16_t* __restrict__ ANg,
                                              const float* __restrict__ x,
                                              const float* __restrict__ y,
                                              const float* __restrict__ weff,
                                              const float* __restrict__ beff,
                                              float* __restrict__ out) {
  __shared__ uint16_t AN[64][34];
  int bid = blockIdx.x;
  int qt = bid & 127, rb = bid >> 7, r = rb >> 1, b = rb & 1;
  int tid = threadIdx.x;
  int w = __builtin_amdgcn_readfirstlane(tid >> 6);
  int l = tid & 63, l31 = l & 31, l5 = l >> 5;

  // stage AN slice [64 ch][32 m]
  {
    int ch = tid >> 3, mi = tid & 7;                 // 4 m per thread
    const uint16_t* srcp = ANg + ((size_t)rb * 64 + ch) * N + qt * 32 + mi * 4;
    uint16_t* d = &AN[ch][mi * 4];
    d[0] = srcp[0]; d[1] = srcp[1]; d[2] = srcp[2]; d[3] = srcp[3];
  }
  __syncthreads();

  int m0 = qt * 32;
  float acc[16];
#pragma unroll
  for (int j = 0; j < 16; ++j) acc[j] = 0.f;
  const float* wrow = weff + (size_t)(r * 64) * 256 + w * 32 + l5 * 16;
  for (int ch = 0; ch < 64; ++ch) {
    float a = bf2f(AN[ch][l31]);
    const float* wr = wrow + (size_t)ch * 256;
#pragma unroll
    for (int j = 0; j < 16; ++j) acc[j] = fmaf(wr[j], a, acc[j]);
  }
  const float* src = r == 0 ? x : y;
  float* outr = out + (size_t)r * 2 * CC * N;
  const float* be = beff + r * 256 + w * 32 + l5 * 16;
#pragma unroll
  for (int j = 0; j < 16; ++j) {
    int o = w * 32 + l5 * 16 + j;
    size_t off = ((size_t)b * CC + o) * N + m0 + l31;
    outr[off] = src[off] + acc[j] + be[j];
  }
}

extern "C" void kernel_launch(void* const* d_in, const int* in_sizes, int n_in,
                              void* d_out, int out_size, void* d_ws, size_t ws_size,
                              hipStream_t stream) {
  const float* x    = (const float*)d_in[0];
  const float* y    = (const float*)d_in[1];
  const float* wf1  = (const float*)d_in[2];
  const float* bf1  = (const float*)d_in[3];
  const float* wg1  = (const float*)d_in[4];
  const float* bg1  = (const float*)d_in[5];
  const float* wh1  = (const float*)d_in[6];
  const float* bh1  = (const float*)d_in[7];
  const float* wf2  = (const float*)d_in[8];
  const float* bf2  = (const float*)d_in[9];
  const float* wg2  = (const float*)d_in[10];
  const float* bg2  = (const float*)d_in[11];
  const float* wh2  = (const float*)d_in[12];
  const float* bh2  = (const float*)d_in[13];
  const float* wv11 = (const float*)d_in[14];
  const float* bv11 = (const float*)d_in[15];
  const float* wv12 = (const float*)d_in[16];
  const float* bv12 = (const float*)d_in[17];
  const float* wv21 = (const float*)d_in[18];
  const float* bv21 = (const float*)d_in[19];
  const float* wv22 = (const float*)d_in[20];
  const float* bv22 = (const float*)d_in[21];
  const float* wo1  = (const float*)d_in[22];
  const float* bo1  = (const float*)d_in[23];
  const float* wo2  = (const float*)d_in[24];
  const float* bo2  = (const float*)d_in[25];

  float* ws   = (float*)d_ws;
  uint16_t* wfragb = (uint16_t*)(ws + OFF_WFRAG);
  float* weff = ws + OFF_WEFF;
  float* beff = ws + OFF_BEFF;
  uint16_t* Qf = (uint16_t*)(ws + OFF_QF);
  uint16_t* Kf = (uint16_t*)(ws + OFF_KF);
  uint16_t* Vf = (uint16_t*)(ws + OFF_VF);
  uint16_t* ANg = (uint16_t*)(ws + OFF_ANG);
  float* out  = (float*)d_out;

  k_prep2<<<322, 256, 0, stream>>>(wf1, wg1, wh1, wf2, wg2, wh2, wo1, wo2,
                                   wv11, wv12, wv21, wv22,
                                   bv11, bv12, bv21, bv22, bo1, bo2,
                                   wfragb, weff, beff);
  k_proj<<<768, 256, 0, stream>>>(x, y, wfragb, bf1, bg1, bh1, bf2, bg2, bh2, Qf, Kf, Vf);
  k_attn8<<<512, 512, 0, stream>>>(Qf, Kf, Vf, ANg);
  k_epi2<<<512, 512, 0, stream>>>(ANg, x, y, weff, beff, out);
}

// Round 13
// 68.319 us; speedup vs baseline: 1.2635x; 1.2635x over previous
//
#include <hip/hip_runtime.h>
#include <hip/hip_bf16.h>
#include <cstdint>

#define N 4096
#define CC 256
#define CH 32
#define L2E 1.4426950408889634f

typedef __attribute__((ext_vector_type(8)))  short short8;
typedef __attribute__((ext_vector_type(16))) float f32x16;
typedef __attribute__((ext_vector_type(4)))  uint32_t u32x4;

// ---- workspace float offsets ----
#define OFF_WFRAG 0            // wfragb [6][16 kb][64 lane][8 j] bf16 (as u16)
#define OFF_WEFF  311296       // weff  [2][64][256] fp32
#define OFF_BEFF  344064       // beff  [2][256] fp32
#define OFF_QF    344576       // Qf [2][2][128 nt][2 half][64 lane][8] bf16 (scaled by log2e)
#define OFF_KF    606720       // Kf [2][2][128 nt][2 half][64 lane][8] bf16
#define OFF_VF    868864       // Vf [2][2][128 nt][2 fr  ][64 lane][8] bf16

__device__ __forceinline__ uint32_t cvtpk_bf16(float lo, float hi) {
  uint32_t r;
  asm("v_cvt_pk_bf16_f32 %0, %1, %2" : "=v"(r) : "v"(lo), "v"(hi));
  return r;
}
__device__ __forceinline__ float bf2f(uint16_t u) {
  return __builtin_bit_cast(float, (uint32_t)u << 16);
}

// D-layout rows (16 regs, row=(r&3)+8*(r>>2)+4*l5, col=l31) -> two bf16 frags
__device__ __forceinline__ void rows_to_frags(const float* p, u32x4& lo, u32x4& hi) {
#pragma unroll
  for (int kh = 0; kh < 2; ++kh) {
    int base = kh * 8;
    uint32_t x0 = cvtpk_bf16(p[base + 0], p[base + 1]);
    uint32_t y0 = cvtpk_bf16(p[base + 4], p[base + 5]);
    asm volatile("v_permlane32_swap_b32 %0, %1" : "+v"(x0), "+v"(y0));
    uint32_t x1 = cvtpk_bf16(p[base + 2], p[base + 3]);
    uint32_t y1 = cvtpk_bf16(p[base + 6], p[base + 7]);
    asm volatile("v_permlane32_swap_b32 %0, %1" : "+v"(x1), "+v"(y1));
    u32x4 r; r[0] = x0; r[1] = x1; r[2] = y0; r[3] = y1;
    if (kh == 0) lo = r; else hi = r;
  }
}

// one 32-key attention step (validated math) + s_setprio around MFMA
// clusters (T5: +4-7% measured on attn with independent waves, m191)
__device__ __forceinline__ void attn_step(short8 ak0, short8 ak1, short8 bv0, short8 bv1,
                                          short8 bq0, short8 bq1,
                                          f32x16& ao, float& lacc, const f32x16& zero16) {
  __builtin_amdgcn_s_setprio(1);
  f32x16 sa = __builtin_amdgcn_mfma_f32_32x32x16_bf16(ak0, bq0, zero16, 0, 0, 0);
  sa = __builtin_amdgcn_mfma_f32_32x32x16_bf16(ak1, bq1, sa, 0, 0, 0);
  __builtin_amdgcn_s_setprio(0);
  float p[16];
#pragma unroll
  for (int r = 0; r < 16; ++r) p[r] = __builtin_amdgcn_exp2f(sa[r]);
  float t0 = 0.f, t1 = 0.f;
#pragma unroll
  for (int r = 0; r < 8; ++r) { t0 += p[2 * r]; t1 += p[2 * r + 1]; }
  lacc += t0 + t1;
  u32x4 lo, hi;
  rows_to_frags(p, lo, hi);
  __builtin_amdgcn_s_setprio(1);
  ao = __builtin_amdgcn_mfma_f32_32x32x16_bf16(__builtin_bit_cast(short8, lo), bv0, ao, 0, 0, 0);
  ao = __builtin_amdgcn_mfma_f32_32x32x16_bf16(__builtin_bit_cast(short8, hi), bv1, ao, 0, 0, 0);
  __builtin_amdgcn_s_setprio(0);
}

// ------------------------------------------------------------------
// 1) prep2: weight MFMA-frag table + Weff/beff directly from wo.
// ------------------------------------------------------------------
__global__ void k_prep2(const float* __restrict__ wf1, const float* __restrict__ wg1,
                        const float* __restrict__ wh1, const float* __restrict__ wf2,
                        const float* __restrict__ wg2, const float* __restrict__ wh2,
                        const float* __restrict__ wo1, const float* __restrict__ wo2,
                        const float* __restrict__ wv11, const float* __restrict__ wv12,
                        const float* __restrict__ wv21, const float* __restrict__ wv22,
                        const float* __restrict__ bv11, const float* __restrict__ bv12,
                        const float* __restrict__ bv21, const float* __restrict__ bv22,
                        const float* __restrict__ bo1, const float* __restrict__ bo2,
                        uint16_t* __restrict__ wfragb, float* __restrict__ weff,
                        float* __restrict__ beff) {
  int bid = blockIdx.x;
  if (bid < 192) {
    int idx = bid * 256 + threadIdx.x;                 // < 49152 u16
    int q = idx >> 13, kb = (idx >> 9) & 15, l = (idx >> 3) & 63, j = idx & 7;
    int ch = l & 31, c = kb * 16 + (l >> 5) * 8 + j;
    const float* w = q == 0 ? wf1 : q == 1 ? wg1 : q == 2 ? wh1
                   : q == 3 ? wf2 : q == 4 ? wg2 : wh2;
    wfragb[idx] = (uint16_t)cvtpk_bf16(w[ch * CC + c], 0.f);
  } else if (bid < 320) {
    int bid2 = bid - 192;
    int r = bid2 >> 6, ch = bid2 & 63, half = ch >> 5, chp = ch & 31;
    int o = threadIdx.x;
    const float* wv = (r == 0) ? (half ? wv12 : wv11) : (half ? wv22 : wv21);
    const float* wrow = (r == 0 ? wo1 : wo2) + (size_t)o * 512 + half * 256;
    float a[8];
#pragma unroll
    for (int u = 0; u < 8; ++u) a[u] = 0.f;
#pragma unroll 4
    for (int c = 0; c < 256; c += 8) {
#pragma unroll
      for (int u = 0; u < 8; ++u)
        a[u] = fmaf(wrow[c + u], wv[(c + u) * CH + chp], a[u]);
    }
    weff[((size_t)r * 64 + ch) * 256 + o] =
        ((a[0] + a[1]) + (a[2] + a[3])) + ((a[4] + a[5]) + (a[6] + a[7]));
  } else {
    int r = bid - 320;
    int o = threadIdx.x;
    const float* bo  = r == 0 ? bo1 : bo2;
    const float* bva = r == 0 ? bv11 : bv21;
    const float* bvb = r == 0 ? bv12 : bv22;
    const float* wrow = (r == 0 ? wo1 : wo2) + (size_t)o * 512;
    float a[4], b4[4];
#pragma unroll
    for (int u = 0; u < 4; ++u) { a[u] = 0.f; b4[u] = 0.f; }
#pragma unroll 8
    for (int c = 0; c < 256; c += 4) {
#pragma unroll
      for (int u = 0; u < 4; ++u) {
        a[u]  = fmaf(wrow[c + u],       bva[c + u], a[u]);
        b4[u] = fmaf(wrow[c + u + 256], bvb[c + u], b4[u]);
      }
    }
    beff[r * 256 + o] = bo[o] + ((a[0] + a[1]) + (a[2] + a[3]))
                              + ((b4[0] + b4[1]) + (b4[2] + b4[3]));
  }
}

// ------------------------------------------------------------------
// 2) projections via MFMA, K-split across wave pairs (validated r10)
// ------------------------------------------------------------------
__global__ __launch_bounds__(256) void k_proj(
    const float* __restrict__ x, const float* __restrict__ y,
    const uint16_t* __restrict__ wfragb,
    const float* __restrict__ bf1, const float* __restrict__ bg1, const float* __restrict__ bh1,
    const float* __restrict__ bf2, const float* __restrict__ bg2, const float* __restrict__ bh2,
    uint16_t* __restrict__ Qf, uint16_t* __restrict__ Kf, uint16_t* __restrict__ Vf) {
  __shared__ float xch[2][64][17];
  int bid = blockIdx.x;
  int w = __builtin_amdgcn_readfirstlane(threadIdx.x >> 6);
  int l = threadIdx.x & 63, l31 = l & 31, l5 = l >> 5;

  int q, ql, b, nt, inst, khalf, pair;
  const float* src;
  const float* bias;
  bool isf, isV;
  if (bid < 512) {
    int chunk = bid >> 1;
    ql = (bid & 1) * 2 + (w >> 1); khalf = w & 1; pair = w >> 1;
    b = chunk >> 7; nt = chunk & 127;
    src = x; inst = 0;
    q = (ql == 3) ? 5 : ql;
    isf = (ql == 0); isV = (ql >= 2);
    bias = ql == 0 ? bf1 : ql == 1 ? bg1 : ql == 2 ? bh1 : bh2;
  } else {
    int u = (bid - 512) * 4 + w;
    int task = u >> 1; khalf = u & 1; pair = w >> 1;
    int chunk = task >> 1; ql = task & 1;
    b = chunk >> 7; nt = chunk & 127;
    src = y; inst = 1;
    q = 3 + ql;
    isf = (ql == 0); isV = false;
    bias = ql == 0 ? bf2 : bg2;
  }

  const u32x4* wp = (const u32x4*)wfragb + (size_t)q * 16 * 64 + (size_t)khalf * 8 * 64 + l;
  u32x4 wfr[8];
#pragma unroll
  for (int kb = 0; kb < 8; ++kb) wfr[kb] = wp[kb * 64];

  const float* sp = src + (size_t)b * CC * N + (size_t)(khalf * 128 + l5 * 8) * N + nt * 32 + l31;
  f32x16 acc;
#pragma unroll
  for (int r = 0; r < 16; ++r) acc[r] = 0.f;

  if (isV) {
#pragma unroll
    for (int kb = 0; kb < 8; ++kb) {
      const float* kp = sp + (size_t)kb * 16 * N;
      float xj[8];
#pragma unroll
      for (int j = 0; j < 8; ++j) xj[j] = kp[(size_t)j * N];
      u32x4 bu;
#pragma unroll
      for (int jh = 0; jh < 4; ++jh) bu[jh] = cvtpk_bf16(xj[2 * jh], xj[2 * jh + 1]);
      acc = __builtin_amdgcn_mfma_f32_32x32x16_bf16(
          __builtin_bit_cast(short8, bu), __builtin_bit_cast(short8, wfr[kb]), acc, 0, 0, 0);
    }
  } else {
#pragma unroll
    for (int kb = 0; kb < 8; ++kb) {
      const float* kp = sp + (size_t)kb * 16 * N;
      float xj[8];
#pragma unroll
      for (int j = 0; j < 8; ++j) xj[j] = kp[(size_t)j * N];
      u32x4 bu;
#pragma unroll
      for (int jh = 0; jh < 4; ++jh) bu[jh] = cvtpk_bf16(xj[2 * jh], xj[2 * jh + 1]);
      acc = __builtin_amdgcn_mfma_f32_32x32x16_bf16(
          __builtin_bit_cast(short8, wfr[kb]), __builtin_bit_cast(short8, bu), acc, 0, 0, 0);
    }
  }

  if (khalf == 1) {
#pragma unroll
    for (int r = 0; r < 16; ++r) xch[pair][l][r] = acc[r];
  }
  __syncthreads();
  if (khalf == 1) return;
#pragma unroll
  for (int r = 0; r < 16; ++r) acc[r] += xch[pair][l][r];

  float p[16];
  if (isV) {
    float bv = bias[l31];
#pragma unroll
    for (int r = 0; r < 16; ++r) p[r] = acc[r] + bv;
  } else {
#pragma unroll
    for (int r = 0; r < 16; ++r) {
      int crow = (r & 3) + 8 * (r >> 2) + 4 * l5;
      float t = acc[r] + bias[crow];
      p[r] = isf ? t * L2E : t;
    }
  }

  u32x4 lo, hi;
  rows_to_frags(p, lo, hi);

  uint16_t* dstb = isV ? Vf : (isf ? Qf : Kf);
  int oinst = isV ? (ql - 2) : inst;               // h1->inst0, h2->inst1
  int b128 = (oinst * 2 + b) * 128 + nt;
  uint32_t* d0 = (uint32_t*)dstb + (size_t)b128 * 512 + l * 4;
  *(u32x4*)d0 = lo;
  *(u32x4*)(d0 + 256) = hi;
}

// ------------------------------------------------------------------
// 3) fused attention + epilogue (r10 structure — best measured, 69.1us):
//    block = (r, b, 64 queries), 512 thr; wave = (ik, kw quarter),
//    2 q-tiles share every K/V load; bf16 LDS (45.6KB); fused Weff epi.
// ------------------------------------------------------------------
__global__ __launch_bounds__(512) void k_attnepi(const uint16_t* __restrict__ Qf,
                                                 const uint16_t* __restrict__ Kf,
                                                 const uint16_t* __restrict__ Vf,
                                                 const float* __restrict__ x,
                                                 const float* __restrict__ y,
                                                 const float* __restrict__ weff,
                                                 const float* __restrict__ beff,
                                                 float* __restrict__ out) {
  __shared__ uint16_t redAO[2][2][4][32][34];  // [ik][qi][kw][query][channel] bf16
  __shared__ float    redL[2][2][4][32];
  __shared__ uint16_t AN[64][66];              // [ch_cat][m local] bf16
  int bid = blockIdx.x;
  int qg = bid & 63, rb = bid >> 6, r = rb >> 1, b = rb & 1;
  int tid = threadIdx.x;
  int w = __builtin_amdgcn_readfirstlane(tid >> 6);
  int ik = w >> 2, kw = w & 3;
  int l = tid & 63, l31 = l & 31, l5 = l >> 5;
  int qt0 = qg * 2, qt1 = qg * 2 + 1;

  const uint16_t* Qp0 = Qf + (size_t)((r * 2 + b) * 128 + qt0) * 1024 + l * 8;
  const uint16_t* Qp1 = Qf + (size_t)((r * 2 + b) * 128 + qt1) * 1024 + l * 8;
  const uint16_t* Kp = Kf + (size_t)((ik * 2 + b) * 128 + kw * 32) * 1024 + l * 8;
  const uint16_t* Vp = Vf + (size_t)((ik * 2 + b) * 128 + kw * 32) * 1024 + l * 8;

  short8 bq00 = *(const short8*)(Qp0);
  short8 bq01 = *(const short8*)(Qp0 + 512);
  short8 bq10 = *(const short8*)(Qp1);
  short8 bq11 = *(const short8*)(Qp1 + 512);

  f32x16 zero16, ao0, ao1;
#pragma unroll
  for (int rr = 0; rr < 16; ++rr) { zero16[rr] = 0.f; ao0[rr] = 0.f; ao1[rr] = 0.f; }
  float lacc0 = 0.f, lacc1 = 0.f;

  for (int t = 0; t < 32; ++t) {
    const uint16_t* kt = Kp + t * 1024;
    short8 ak0 = *(const short8*)(kt);
    short8 ak1 = *(const short8*)(kt + 512);
    const uint16_t* vt = Vp + t * 1024;
    short8 bv0 = *(const short8*)(vt);
    short8 bv1 = *(const short8*)(vt + 512);
    attn_step(ak0, ak1, bv0, bv1, bq00, bq01, ao0, lacc0, zero16);
    attn_step(ak0, ak1, bv0, bv1, bq10, bq11, ao1, lacc1, zero16);
  }

  // per-wave partials -> LDS (bf16)  (row = query, col = channel)
#pragma unroll
  for (int rr = 0; rr < 16; ++rr) {
    int row = (rr & 3) + 8 * (rr >> 2) + 4 * l5;
    redAO[ik][0][kw][row][l31] = (uint16_t)cvtpk_bf16(ao0[rr], ao0[rr]);
    redAO[ik][1][kw][row][l31] = (uint16_t)cvtpk_bf16(ao1[rr], ao1[rr]);
  }
  lacc0 += __shfl_xor(lacc0, 32);
  lacc1 += __shfl_xor(lacc1, 32);
  if (l < 32) {
    redL[ik][0][kw][l31] = lacc0;
    redL[ik][1][kw][l31] = lacc1;
  }
  __syncthreads();

  // combine over kw + normalize into AN[ch_cat][m] (bf16)
  {
    int ch = tid >> 3, mblk = tid & 7;
    int qi = mblk >> 2, mq0 = (mblk & 3) * 8;
    int ikc = ch >> 5, chp = ch & 31;
#pragma unroll
    for (int mm = 0; mm < 8; ++mm) {
      int mq = mq0 + mm;
      float L = redL[ikc][qi][0][mq] + redL[ikc][qi][1][mq]
              + redL[ikc][qi][2][mq] + redL[ikc][qi][3][mq];
      float s = bf2f(redAO[ikc][qi][0][mq][chp]) + bf2f(redAO[ikc][qi][1][mq][chp])
              + bf2f(redAO[ikc][qi][2][mq][chp]) + bf2f(redAO[ikc][qi][3][mq][chp]);
      float v = s * __builtin_amdgcn_rcpf(L);
      AN[ch][qi * 32 + mq] = (uint16_t)cvtpk_bf16(v, v);
    }
  }
  __syncthreads();

  // epilogue: wave w owns outputs o = w*32 .. w*32+31; lane = m
  int m = tid & 63;
  int m0 = qg * 64;
  float acc[32];
#pragma unroll
  for (int j = 0; j < 32; ++j) acc[j] = 0.f;
  const float* wrow = weff + (size_t)(r * 64) * 256 + w * 32;
  for (int ch = 0; ch < 64; ++ch) {
    float a = bf2f(AN[ch][m]);
    const float* wr = wrow + (size_t)ch * 256;
#pragma unroll
    for (int j = 0; j < 32; ++j) acc[j] = fmaf(wr[j], a, acc[j]);
  }
  const float* src = r == 0 ? x : y;
  float* outr = out + (size_t)r * 2 * CC * N;
  const float* be = beff + r * 256 + w * 32;
#pragma unroll
  for (int j = 0; j < 32; ++j) {
    size_t off = ((size_t)b * CC + w * 32 + j) * N + m0 + m;
    outr[off] = src[off] + acc[j] + be[j];
  }
}

extern "C" void kernel_launch(void* const* d_in, const int* in_sizes, int n_in,
                              void* d_out, int out_size, void* d_ws, size_t ws_size,
                              hipStream_t stream) {
  const float* x    = (const float*)d_in[0];
  const float* y    = (const float*)d_in[1];
  const float* wf1  = (const float*)d_in[2];
  const float* bf1  = (const float*)d_in[3];
  const float* wg1  = (const float*)d_in[4];
  const float* bg1  = (const float*)d_in[5];
  const float* wh1  = (const float*)d_in[6];
  const float* bh1  = (const float*)d_in[7];
  const float* wf2  = (const float*)d_in[8];
  const float* bf2  = (const float*)d_in[9];
  const float* wg2  = (const float*)d_in[10];
  const float* bg2  = (const float*)d_in[11];
  const float* wh2  = (const float*)d_in[12];
  const float* bh2  = (const float*)d_in[13];
  const float* wv11 = (const float*)d_in[14];
  const float* bv11 = (const float*)d_in[15];
  const float* wv12 = (const float*)d_in[16];
  const float* bv12 = (const float*)d_in[17];
  const float* wv21 = (const float*)d_in[18];
  const float* bv21 = (const float*)d_in[19];
  const float* wv22 = (const float*)d_in[20];
  const float* bv22 = (const float*)d_in[21];
  const float* wo1  = (const float*)d_in[22];
  const float* bo1  = (const float*)d_in[23];
  const float* wo2  = (const float*)d_in[24];
  const float* bo2  = (const float*)d_in[25];

  float* ws   = (float*)d_ws;
  uint16_t* wfragb = (uint16_t*)(ws + OFF_WFRAG);
  float* weff = ws + OFF_WEFF;
  float* beff = ws + OFF_BEFF;
  uint16_t* Qf = (uint16_t*)(ws + OFF_QF);
  uint16_t* Kf = (uint16_t*)(ws + OFF_KF);
  uint16_t* Vf = (uint16_t*)(ws + OFF_VF);
  float* out  = (float*)d_out;

  k_prep2<<<322, 256, 0, stream>>>(wf1, wg1, wh1, wf2, wg2, wh2, wo1, wo2,
                                   wv11, wv12, wv21, wv22,
                                   bv11, bv12, bv21, bv22, bo1, bo2,
                                   wfragb, weff, beff);
  k_proj<<<768, 256, 0, stream>>>(x, y, wfragb, bf1, bg1, bh1, bf2, bg2, bh2, Qf, Kf, Vf);
  k_attnepi<<<256, 512, 0, stream>>>(Qf, Kf, Vf, x, y, weff, beff, out);
}

// Round 14
// 66.483 us; speedup vs baseline: 1.2984x; 1.0276x over previous
//
#include <hip/hip_runtime.h>
#include <hip/hip_bf16.h>
#include <cstdint>

#define N 4096
#define CC 256
#define CH 32
#define L2E 1.4426950408889634f

typedef __attribute__((ext_vector_type(8)))  short short8;
typedef __attribute__((ext_vector_type(16))) float f32x16;
typedef __attribute__((ext_vector_type(4)))  uint32_t u32x4;

// ---- workspace float offsets ----
#define OFF_WFRAG 0            // wfragb [6][16 kb][64 lane][8 j] bf16 (as u16)
#define OFF_WEFF  311296       // weff  [2][64][256] fp32
#define OFF_BEFF  344064       // beff  [2][256] fp32
#define OFF_QF    344576       // Qf [2][2][128 nt][2 half][64 lane][8] bf16 (scaled by log2e)
#define OFF_KF    606720       // Kf [2][2][128 nt][2 half][64 lane][8] bf16
#define OFF_VF    868864       // Vf [2][2][128 nt][2 fr  ][64 lane][8] bf16

__device__ __forceinline__ uint32_t cvtpk_bf16(float lo, float hi) {
  uint32_t r;
  asm("v_cvt_pk_bf16_f32 %0, %1, %2" : "=v"(r) : "v"(lo), "v"(hi));
  return r;
}
__device__ __forceinline__ float bf2f(uint16_t u) {
  return __builtin_bit_cast(float, (uint32_t)u << 16);
}

// D-layout rows (16 regs, row=(r&3)+8*(r>>2)+4*l5, col=l31) -> two bf16 frags
__device__ __forceinline__ void rows_to_frags(const float* p, u32x4& lo, u32x4& hi) {
#pragma unroll
  for (int kh = 0; kh < 2; ++kh) {
    int base = kh * 8;
    uint32_t x0 = cvtpk_bf16(p[base + 0], p[base + 1]);
    uint32_t y0 = cvtpk_bf16(p[base + 4], p[base + 5]);
    asm volatile("v_permlane32_swap_b32 %0, %1" : "+v"(x0), "+v"(y0));
    uint32_t x1 = cvtpk_bf16(p[base + 2], p[base + 3]);
    uint32_t y1 = cvtpk_bf16(p[base + 6], p[base + 7]);
    asm volatile("v_permlane32_swap_b32 %0, %1" : "+v"(x1), "+v"(y1));
    u32x4 r; r[0] = x0; r[1] = x1; r[2] = y0; r[3] = y1;
    if (kh == 0) lo = r; else hi = r;
  }
}

// one 32-key attention step (validated math) + s_setprio around MFMA
// clusters (T5: measured +2-3% here, r13)
__device__ __forceinline__ void attn_step(short8 ak0, short8 ak1, short8 bv0, short8 bv1,
                                          short8 bq0, short8 bq1,
                                          f32x16& ao, float& lacc, const f32x16& zero16) {
  __builtin_amdgcn_s_setprio(1);
  f32x16 sa = __builtin_amdgcn_mfma_f32_32x32x16_bf16(ak0, bq0, zero16, 0, 0, 0);
  sa = __builtin_amdgcn_mfma_f32_32x32x16_bf16(ak1, bq1, sa, 0, 0, 0);
  __builtin_amdgcn_s_setprio(0);
  float p[16];
#pragma unroll
  for (int r = 0; r < 16; ++r) p[r] = __builtin_amdgcn_exp2f(sa[r]);
  float t0 = 0.f, t1 = 0.f;
#pragma unroll
  for (int r = 0; r < 8; ++r) { t0 += p[2 * r]; t1 += p[2 * r + 1]; }
  lacc += t0 + t1;
  u32x4 lo, hi;
  rows_to_frags(p, lo, hi);
  __builtin_amdgcn_s_setprio(1);
  ao = __builtin_amdgcn_mfma_f32_32x32x16_bf16(__builtin_bit_cast(short8, lo), bv0, ao, 0, 0, 0);
  ao = __builtin_amdgcn_mfma_f32_32x32x16_bf16(__builtin_bit_cast(short8, hi), bv1, ao, 0, 0, 0);
  __builtin_amdgcn_s_setprio(0);
}

// ------------------------------------------------------------------
// 1) prep2: weight MFMA-frag table + Weff/beff directly from wo.
// ------------------------------------------------------------------
__global__ void k_prep2(const float* __restrict__ wf1, const float* __restrict__ wg1,
                        const float* __restrict__ wh1, const float* __restrict__ wf2,
                        const float* __restrict__ wg2, const float* __restrict__ wh2,
                        const float* __restrict__ wo1, const float* __restrict__ wo2,
                        const float* __restrict__ wv11, const float* __restrict__ wv12,
                        const float* __restrict__ wv21, const float* __restrict__ wv22,
                        const float* __restrict__ bv11, const float* __restrict__ bv12,
                        const float* __restrict__ bv21, const float* __restrict__ bv22,
                        const float* __restrict__ bo1, const float* __restrict__ bo2,
                        uint16_t* __restrict__ wfragb, float* __restrict__ weff,
                        float* __restrict__ beff) {
  int bid = blockIdx.x;
  if (bid < 192) {
    int idx = bid * 256 + threadIdx.x;                 // < 49152 u16
    int q = idx >> 13, kb = (idx >> 9) & 15, l = (idx >> 3) & 63, j = idx & 7;
    int ch = l & 31, c = kb * 16 + (l >> 5) * 8 + j;
    const float* w = q == 0 ? wf1 : q == 1 ? wg1 : q == 2 ? wh1
                   : q == 3 ? wf2 : q == 4 ? wg2 : wh2;
    wfragb[idx] = (uint16_t)cvtpk_bf16(w[ch * CC + c], 0.f);
  } else if (bid < 320) {
    int bid2 = bid - 192;
    int r = bid2 >> 6, ch = bid2 & 63, half = ch >> 5, chp = ch & 31;
    int o = threadIdx.x;
    const float* wv = (r == 0) ? (half ? wv12 : wv11) : (half ? wv22 : wv21);
    const float* wrow = (r == 0 ? wo1 : wo2) + (size_t)o * 512 + half * 256;
    float a[8];
#pragma unroll
    for (int u = 0; u < 8; ++u) a[u] = 0.f;
#pragma unroll 4
    for (int c = 0; c < 256; c += 8) {
#pragma unroll
      for (int u = 0; u < 8; ++u)
        a[u] = fmaf(wrow[c + u], wv[(c + u) * CH + chp], a[u]);
    }
    weff[((size_t)r * 64 + ch) * 256 + o] =
        ((a[0] + a[1]) + (a[2] + a[3])) + ((a[4] + a[5]) + (a[6] + a[7]));
  } else {
    int r = bid - 320;
    int o = threadIdx.x;
    const float* bo  = r == 0 ? bo1 : bo2;
    const float* bva = r == 0 ? bv11 : bv21;
    const float* bvb = r == 0 ? bv12 : bv22;
    const float* wrow = (r == 0 ? wo1 : wo2) + (size_t)o * 512;
    float a[4], b4[4];
#pragma unroll
    for (int u = 0; u < 4; ++u) { a[u] = 0.f; b4[u] = 0.f; }
#pragma unroll 8
    for (int c = 0; c < 256; c += 4) {
#pragma unroll
      for (int u = 0; u < 4; ++u) {
        a[u]  = fmaf(wrow[c + u],       bva[c + u], a[u]);
        b4[u] = fmaf(wrow[c + u + 256], bvb[c + u], b4[u]);
      }
    }
    beff[r * 256 + o] = bo[o] + ((a[0] + a[1]) + (a[2] + a[3]))
                              + ((b4[0] + b4[1]) + (b4[2] + b4[3]));
  }
}

// ------------------------------------------------------------------
// 2) projections via MFMA, K-split across wave pairs (validated r10)
// ------------------------------------------------------------------
__global__ __launch_bounds__(256) void k_proj(
    const float* __restrict__ x, const float* __restrict__ y,
    const uint16_t* __restrict__ wfragb,
    const float* __restrict__ bf1, const float* __restrict__ bg1, const float* __restrict__ bh1,
    const float* __restrict__ bf2, const float* __restrict__ bg2, const float* __restrict__ bh2,
    uint16_t* __restrict__ Qf, uint16_t* __restrict__ Kf, uint16_t* __restrict__ Vf) {
  __shared__ float xch[2][64][17];
  int bid = blockIdx.x;
  int w = __builtin_amdgcn_readfirstlane(threadIdx.x >> 6);
  int l = threadIdx.x & 63, l31 = l & 31, l5 = l >> 5;

  int q, ql, b, nt, inst, khalf, pair;
  const float* src;
  const float* bias;
  bool isf, isV;
  if (bid < 512) {
    int chunk = bid >> 1;
    ql = (bid & 1) * 2 + (w >> 1); khalf = w & 1; pair = w >> 1;
    b = chunk >> 7; nt = chunk & 127;
    src = x; inst = 0;
    q = (ql == 3) ? 5 : ql;
    isf = (ql == 0); isV = (ql >= 2);
    bias = ql == 0 ? bf1 : ql == 1 ? bg1 : ql == 2 ? bh1 : bh2;
  } else {
    int u = (bid - 512) * 4 + w;
    int task = u >> 1; khalf = u & 1; pair = w >> 1;
    int chunk = task >> 1; ql = task & 1;
    b = chunk >> 7; nt = chunk & 127;
    src = y; inst = 1;
    q = 3 + ql;
    isf = (ql == 0); isV = false;
    bias = ql == 0 ? bf2 : bg2;
  }

  const u32x4* wp = (const u32x4*)wfragb + (size_t)q * 16 * 64 + (size_t)khalf * 8 * 64 + l;
  u32x4 wfr[8];
#pragma unroll
  for (int kb = 0; kb < 8; ++kb) wfr[kb] = wp[kb * 64];

  const float* sp = src + (size_t)b * CC * N + (size_t)(khalf * 128 + l5 * 8) * N + nt * 32 + l31;
  f32x16 acc;
#pragma unroll
  for (int r = 0; r < 16; ++r) acc[r] = 0.f;

  if (isV) {
#pragma unroll
    for (int kb = 0; kb < 8; ++kb) {
      const float* kp = sp + (size_t)kb * 16 * N;
      float xj[8];
#pragma unroll
      for (int j = 0; j < 8; ++j) xj[j] = kp[(size_t)j * N];
      u32x4 bu;
#pragma unroll
      for (int jh = 0; jh < 4; ++jh) bu[jh] = cvtpk_bf16(xj[2 * jh], xj[2 * jh + 1]);
      acc = __builtin_amdgcn_mfma_f32_32x32x16_bf16(
          __builtin_bit_cast(short8, bu), __builtin_bit_cast(short8, wfr[kb]), acc, 0, 0, 0);
    }
  } else {
#pragma unroll
    for (int kb = 0; kb < 8; ++kb) {
      const float* kp = sp + (size_t)kb * 16 * N;
      float xj[8];
#pragma unroll
      for (int j = 0; j < 8; ++j) xj[j] = kp[(size_t)j * N];
      u32x4 bu;
#pragma unroll
      for (int jh = 0; jh < 4; ++jh) bu[jh] = cvtpk_bf16(xj[2 * jh], xj[2 * jh + 1]);
      acc = __builtin_amdgcn_mfma_f32_32x32x16_bf16(
          __builtin_bit_cast(short8, wfr[kb]), __builtin_bit_cast(short8, bu), acc, 0, 0, 0);
    }
  }

  if (khalf == 1) {
#pragma unroll
    for (int r = 0; r < 16; ++r) xch[pair][l][r] = acc[r];
  }
  __syncthreads();
  if (khalf == 1) return;
#pragma unroll
  for (int r = 0; r < 16; ++r) acc[r] += xch[pair][l][r];

  float p[16];
  if (isV) {
    float bv = bias[l31];
#pragma unroll
    for (int r = 0; r < 16; ++r) p[r] = acc[r] + bv;
  } else {
#pragma unroll
    for (int r = 0; r < 16; ++r) {
      int crow = (r & 3) + 8 * (r >> 2) + 4 * l5;
      float t = acc[r] + bias[crow];
      p[r] = isf ? t * L2E : t;
    }
  }

  u32x4 lo, hi;
  rows_to_frags(p, lo, hi);

  uint16_t* dstb = isV ? Vf : (isf ? Qf : Kf);
  int oinst = isV ? (ql - 2) : inst;               // h1->inst0, h2->inst1
  int b128 = (oinst * 2 + b) * 128 + nt;
  uint32_t* d0 = (uint32_t*)dstb + (size_t)b128 * 512 + l * 4;
  *(u32x4*)d0 = lo;
  *(u32x4*)(d0 + 256) = hi;
}

// ------------------------------------------------------------------
// 3) fused attention + epilogue (r10 structure + r13 setprio), r14:
//    __launch_bounds__(512, 2) lifts the VGPR cap (grid=1 block/CU pins
//    occupancy anyway; VGPR was 64 => no prefetch room) + explicit
//    1-deep register prefetch of next K/V tile (branchless clamp) so
//    L2 latency hides under ~2 attn_steps of compute.
// ------------------------------------------------------------------
__global__ __launch_bounds__(512, 2) void k_attnepi(const uint16_t* __restrict__ Qf,
                                                    const uint16_t* __restrict__ Kf,
                                                    const uint16_t* __restrict__ Vf,
                                                    const float* __restrict__ x,
                                                    const float* __restrict__ y,
                                                    const float* __restrict__ weff,
                                                    const float* __restrict__ beff,
                                                    float* __restrict__ out) {
  __shared__ uint16_t redAO[2][2][4][32][34];  // [ik][qi][kw][query][channel] bf16
  __shared__ float    redL[2][2][4][32];
  __shared__ uint16_t AN[64][66];              // [ch_cat][m local] bf16
  int bid = blockIdx.x;
  int qg = bid & 63, rb = bid >> 6, r = rb >> 1, b = rb & 1;
  int tid = threadIdx.x;
  int w = __builtin_amdgcn_readfirstlane(tid >> 6);
  int ik = w >> 2, kw = w & 3;
  int l = tid & 63, l31 = l & 31, l5 = l >> 5;
  int qt0 = qg * 2, qt1 = qg * 2 + 1;

  const uint16_t* Qp0 = Qf + (size_t)((r * 2 + b) * 128 + qt0) * 1024 + l * 8;
  const uint16_t* Qp1 = Qf + (size_t)((r * 2 + b) * 128 + qt1) * 1024 + l * 8;
  const uint16_t* Kp = Kf + (size_t)((ik * 2 + b) * 128 + kw * 32) * 1024 + l * 8;
  const uint16_t* Vp = Vf + (size_t)((ik * 2 + b) * 128 + kw * 32) * 1024 + l * 8;

  short8 bq00 = *(const short8*)(Qp0);
  short8 bq01 = *(const short8*)(Qp0 + 512);
  short8 bq10 = *(const short8*)(Qp1);
  short8 bq11 = *(const short8*)(Qp1 + 512);

  f32x16 zero16, ao0, ao1;
#pragma unroll
  for (int rr = 0; rr < 16; ++rr) { zero16[rr] = 0.f; ao0[rr] = 0.f; ao1[rr] = 0.f; }
  float lacc0 = 0.f, lacc1 = 0.f;

  // software-pipelined main loop: prefetch t+1 while computing t
  short8 ak0 = *(const short8*)(Kp);
  short8 ak1 = *(const short8*)(Kp + 512);
  short8 bv0 = *(const short8*)(Vp);
  short8 bv1 = *(const short8*)(Vp + 512);
  for (int t = 0; t < 32; ++t) {
    int tn = (t + 1) & 31;                     // clamp: last iter reloads t=0 (discarded)
    const uint16_t* nkt = Kp + tn * 1024;
    const uint16_t* nvt = Vp + tn * 1024;
    short8 nak0 = *(const short8*)(nkt);
    short8 nak1 = *(const short8*)(nkt + 512);
    short8 nbv0 = *(const short8*)(nvt);
    short8 nbv1 = *(const short8*)(nvt + 512);
    attn_step(ak0, ak1, bv0, bv1, bq00, bq01, ao0, lacc0, zero16);
    attn_step(ak0, ak1, bv0, bv1, bq10, bq11, ao1, lacc1, zero16);
    ak0 = nak0; ak1 = nak1; bv0 = nbv0; bv1 = nbv1;
  }

  // per-wave partials -> LDS (bf16)  (row = query, col = channel)
#pragma unroll
  for (int rr = 0; rr < 16; ++rr) {
    int row = (rr & 3) + 8 * (rr >> 2) + 4 * l5;
    redAO[ik][0][kw][row][l31] = (uint16_t)cvtpk_bf16(ao0[rr], ao0[rr]);
    redAO[ik][1][kw][row][l31] = (uint16_t)cvtpk_bf16(ao1[rr], ao1[rr]);
  }
  lacc0 += __shfl_xor(lacc0, 32);
  lacc1 += __shfl_xor(lacc1, 32);
  if (l < 32) {
    redL[ik][0][kw][l31] = lacc0;
    redL[ik][1][kw][l31] = lacc1;
  }
  __syncthreads();

  // combine over kw + normalize into AN[ch_cat][m] (bf16)
  {
    int ch = tid >> 3, mblk = tid & 7;
    int qi = mblk >> 2, mq0 = (mblk & 3) * 8;
    int ikc = ch >> 5, chp = ch & 31;
#pragma unroll
    for (int mm = 0; mm < 8; ++mm) {
      int mq = mq0 + mm;
      float L = redL[ikc][qi][0][mq] + redL[ikc][qi][1][mq]
              + redL[ikc][qi][2][mq] + redL[ikc][qi][3][mq];
      float s = bf2f(redAO[ikc][qi][0][mq][chp]) + bf2f(redAO[ikc][qi][1][mq][chp])
              + bf2f(redAO[ikc][qi][2][mq][chp]) + bf2f(redAO[ikc][qi][3][mq][chp]);
      float v = s * __builtin_amdgcn_rcpf(L);
      AN[ch][qi * 32 + mq] = (uint16_t)cvtpk_bf16(v, v);
    }
  }
  __syncthreads();

  // epilogue: wave w owns outputs o = w*32 .. w*32+31; lane = m
  int m = tid & 63;
  int m0 = qg * 64;
  float acc[32];
#pragma unroll
  for (int j = 0; j < 32; ++j) acc[j] = 0.f;
  const float* wrow = weff + (size_t)(r * 64) * 256 + w * 32;
  for (int ch = 0; ch < 64; ++ch) {
    float a = bf2f(AN[ch][m]);
    const float* wr = wrow + (size_t)ch * 256;
#pragma unroll
    for (int j = 0; j < 32; ++j) acc[j] = fmaf(wr[j], a, acc[j]);
  }
  const float* src = r == 0 ? x : y;
  float* outr = out + (size_t)r * 2 * CC * N;
  const float* be = beff + r * 256 + w * 32;
#pragma unroll
  for (int j = 0; j < 32; ++j) {
    size_t off = ((size_t)b * CC + w * 32 + j) * N + m0 + m;
    outr[off] = src[off] + acc[j] + be[j];
  }
}

extern "C" void kernel_launch(void* const* d_in, const int* in_sizes, int n_in,
                              void* d_out, int out_size, void* d_ws, size_t ws_size,
                              hipStream_t stream) {
  const float* x    = (const float*)d_in[0];
  const float* y    = (const float*)d_in[1];
  const float* wf1  = (const float*)d_in[2];
  const float* bf1  = (const float*)d_in[3];
  const float* wg1  = (const float*)d_in[4];
  const float* bg1  = (const float*)d_in[5];
  const float* wh1  = (const float*)d_in[6];
  const float* bh1  = (const float*)d_in[7];
  const float* wf2  = (const float*)d_in[8];
  const float* bf2  = (const float*)d_in[9];
  const float* wg2  = (const float*)d_in[10];
  const float* bg2  = (const float*)d_in[11];
  const float* wh2  = (const float*)d_in[12];
  const float* bh2  = (const float*)d_in[13];
  const float* wv11 = (const float*)d_in[14];
  const float* bv11 = (const float*)d_in[15];
  const float* wv12 = (const float*)d_in[16];
  const float* bv12 = (const float*)d_in[17];
  const float* wv21 = (const float*)d_in[18];
  const float* bv21 = (const float*)d_in[19];
  const float* wv22 = (const float*)d_in[20];
  const float* bv22 = (const float*)d_in[21];
  const float* wo1  = (const float*)d_in[22];
  const float* bo1  = (const float*)d_in[23];
  const float* wo2  = (const float*)d_in[24];
  const float* bo2  = (const float*)d_in[25];

  float* ws   = (float*)d_ws;
  uint16_t* wfragb = (uint16_t*)(ws + OFF_WFRAG);
  float* weff = ws + OFF_WEFF;
  float* beff = ws + OFF_BEFF;
  uint16_t* Qf = (uint16_t*)(ws + OFF_QF);
  uint16_t* Kf = (uint16_t*)(ws + OFF_KF);
  uint16_t* Vf = (uint16_t*)(ws + OFF_VF);
  float* out  = (float*)d_out;

  k_prep2<<<322, 256, 0, stream>>>(wf1, wg1, wh1, wf2, wg2, wh2, wo1, wo2,
                                   wv11, wv12, wv21, wv22,
                                   bv11, bv12, bv21, bv22, bo1, bo2,
                                   wfragb, weff, beff);
  k_proj<<<768, 256, 0, stream>>>(x, y, wfragb, bf1, bg1, bh1, bf2, bg2, bh2, Qf, Kf, Vf);
  k_attnepi<<<256, 512, 0, stream>>>(Qf, Kf, Vf, x, y, weff, beff, out);
}